// Round 6
// baseline (247.020 us; speedup 1.0000x reference)
//
#include <hip/hip_runtime.h>
#include <hip/hip_bf16.h>

#define NN 50000
#define KI 8
#define H 128
#define XD 32
#define SD 27
#define CIN 416      // original combined width
#define CIN2 320     // fused combined: x(32)|h(128)|nc(128)|static(27)|pad(5)
#define CPAD 328     // LDS row stride (shorts)
#define ZOUT 512
#define NTILE_NB (NN / KI)   // 6250 tiles of 8 nodes
#define MB_LSTM 32           // nodes per k_lstm block
#define GRID_NB 1024

typedef __attribute__((ext_vector_type(8))) short bf16x8;
typedef __attribute__((ext_vector_type(4))) float f32x4;
typedef __attribute__((ext_vector_type(4))) unsigned short us4;

#define MFMA16(a, b, c) __builtin_amdgcn_mfma_f32_16x16x32_bf16((a), (b), (c), 0, 0, 0)

static __device__ __forceinline__ float sigmoidf_(float x) {
    return 1.0f / (1.0f + __expf(-x));
}
// fast tanh, saturation-safe: 1 - 2/(e^{2x}+1)
static __device__ __forceinline__ float tanhf_(float x) {
    return 1.0f - 2.0f / (__expf(2.0f * x) + 1.0f);
}
// f32 -> bf16 via HW cvt (compiler emits v_cvt_pk_bf16_f32 for pairs)
static __device__ __forceinline__ unsigned short bf(float f) {
    __hip_bfloat16 h = __float2bfloat16(f);
    return __builtin_bit_cast(unsigned short, h);
}
static __device__ __forceinline__ float dot4_(float4 a, float4 b) {
    return a.x * b.x + a.y * b.y + a.z * b.z + a.w * b.w;
}

// ---------------------------------------------------------------------------
// Prep: bf16 weights + fused LSTM weight W' and bias b'.
// ---------------------------------------------------------------------------
__global__ __launch_bounds__(256) void k_prep(
    const float* __restrict__ Wn, const float* __restrict__ Wg,
    const float* __restrict__ Wl, const float* __restrict__ bl,
    const float* __restrict__ Ws, const float* __restrict__ bs,
    unsigned short* __restrict__ WnB, unsigned short* __restrict__ WgB,
    unsigned short* __restrict__ WpB, float* __restrict__ bp)
{
    const int b = blockIdx.x, t = threadIdx.x;
    if (b < 512) {
        const float* wr = Wl + (size_t)b * CIN;
        unsigned short* out = WpB + (size_t)b * CIN2;
        for (int c = t; c < CIN2; c += 256) {
            float v;
            if (c < 288) v = wr[c];
            else if (c < 288 + SD) {
                int s = c - 288;
                float acc = 0.f;
                for (int j = 0; j < H; ++j) acc += wr[288 + j] * Ws[j * SD + s];
                v = acc;
            } else v = 0.f;
            out[c] = bf(v);
        }
        if (t == 0) {
            float acc = bl[b];
            for (int j = 0; j < H; ++j) acc += wr[288 + j] * bs[j];
            bp[b] = acc;
        }
    } else {
        int idx = (b - 512) * 256 + t;
        for (int r = idx; r < 49152; r += 16384) {
            if (r < 16384) WnB[r] = bf(Wn[r]);
            else WgB[r - 16384] = bf(Wg[r - 16384]);
        }
    }
}

// ---------------------------------------------------------------------------
// Neighbor context via MFMA. Occupancy-first design:
//  - 256 threads (4 waves); wave w owns h-cols [w*32, w*32+32).
//  - B fragments reloaded from L2 per kk (weights are L2-resident, 96KB).
//  - 4 m-tiles split into 2 passes -> ~40 live AGPR, ~120 total regs
//    -> 4 waves/SIMD (16 waves/CU, 4 blocks/CU).
//  - grid-stride over 6250 8-node tiles.
// ---------------------------------------------------------------------------
__global__ __launch_bounds__(256, 3) void k_nb_mfma(
    const float* __restrict__ hself_g, const float* __restrict__ hin_g,
    const unsigned char* __restrict__ valid_raw,
    const unsigned short* __restrict__ WnB, const unsigned short* __restrict__ WgB,
    const float* __restrict__ bg,
    unsigned short* __restrict__ ncb, int nc_stride)
{
    __shared__ unsigned short hin_s[64 * 128];  // XOR-swizzled, 16KB
    __shared__ unsigned short hs_s[8 * 128];    // XOR-swizzled, 2KB
    __shared__ float gh_s[8][128];              // 4KB
    __shared__ unsigned short ncs[8 * 128];     // 2KB
    __shared__ float valid_s[64];

    const int t = threadIdx.x;
    const int w = t >> 6, l = t & 63;
    const int ln = l & 15, lk = l >> 4;

    // detect inflow_valid element width (bool8 vs 4-byte) — uniform, once
    int det = 0;
    #pragma unroll
    for (int i = 0; i < 64; ++i) det |= valid_raw[4 * i + 1];
    const bool f8 = (det != 0);

    const int cbase = w * 32;
    const float bg0 = bg[cbase + ln];
    const float bg1 = bg[cbase + 16 + ln];

    for (int tile = blockIdx.x; tile < NTILE_NB; tile += gridDim.x) {
        const int nb = tile * 8;

        // ---- stage h_inflows + h_self as swizzled bf16 ----
        if (t < 64)
            valid_s[t] = (f8 ? (valid_raw[(size_t)nb * KI + t] != 0)
                             : (((const unsigned int*)valid_raw)[(size_t)nb * KI + t] != 0u))
                             ? 1.f : 0.f;
        {
            const float4* src = (const float4*)(hin_g + (size_t)nb * KI * H);
            float4 r0[8];
            #pragma unroll
            for (int i = 0; i < 8; ++i) r0[i] = src[t + i * 256];
            float4 hv = ((const float4*)(hself_g + (size_t)nb * H))[t];
            #pragma unroll
            for (int i = 0; i < 8; ++i) {
                int e = (t + i * 256) * 4, row = e >> 7, col = e & 127;
                unsigned byte = (unsigned)(row * 256 + col * 2) ^ (unsigned)((row & 7) << 4);
                us4 pk = { bf(r0[i].x), bf(r0[i].y), bf(r0[i].z), bf(r0[i].w) };
                *(us4*)((char*)hin_s + byte) = pk;
            }
            {
                int e = t * 4, row = e >> 7, col = e & 127;
                unsigned byte = (unsigned)(row * 256 + col * 2) ^ (unsigned)((row & 7) << 4);
                us4 pk = { bf(hv.x), bf(hv.y), bf(hv.z), bf(hv.w) };
                *(us4*)((char*)hs_s + byte) = pk;
            }
        }
        __syncthreads();   // B1: tile staged

        // ================= PASS 0: m-tiles 0,1 + gh =================
        f32x4 aM[2][2], aP[2][2], aG[2];
        #pragma unroll
        for (int mm = 0; mm < 2; ++mm)
            #pragma unroll
            for (int c = 0; c < 2; ++c) { aM[mm][c] = (f32x4)0.f; aP[mm][c] = (f32x4)0.f; }
        aG[0] = (f32x4)0.f; aG[1] = (f32x4)0.f;

        #pragma unroll
        for (int kk = 0; kk < 4; ++kk) {
            const int k0 = kk * 32 + lk * 8;
            bf16x8 am0, am1, ah;
            {
                int row = ln;
                unsigned byte = (unsigned)(row * 256 + k0 * 2) ^ (unsigned)((row & 7) << 4);
                am0 = *(const bf16x8*)((const char*)hin_s + byte);
            }
            {
                int row = 16 + ln;
                unsigned byte = (unsigned)(row * 256 + k0 * 2) ^ (unsigned)((row & 7) << 4);
                am1 = *(const bf16x8*)((const char*)hin_s + byte);
            }
            {
                int row = ln & 7;
                unsigned byte = (unsigned)(row * 256 + k0 * 2) ^ (unsigned)((row & 7) << 4);
                ah = *(const bf16x8*)((const char*)hs_s + byte);
            }
            #pragma unroll
            for (int c = 0; c < 2; ++c) {
                const int col = cbase + c * 16 + ln;
                bf16x8 bn = *(const bf16x8*)(WnB + col * H + k0);
                bf16x8 ba = *(const bf16x8*)(WgB + col * 2 * H + k0);
                bf16x8 bb = *(const bf16x8*)(WgB + col * 2 * H + H + k0);
                aM[0][c] = MFMA16(am0, bn, aM[0][c]);
                aM[1][c] = MFMA16(am1, bn, aM[1][c]);
                aP[0][c] = MFMA16(am0, ba, aP[0][c]);
                aP[1][c] = MFMA16(am1, ba, aP[1][c]);
                aG[c]    = MFMA16(ah, bb, aG[c]);
            }
        }

        #pragma unroll
        for (int c = 0; c < 2; ++c)
            #pragma unroll
            for (int r = 0; r < 4; ++r) {
                int row = lk * 4 + r;
                if (row < 8) gh_s[row][cbase + c * 16 + ln] = aG[c][r];
            }
        __syncthreads();   // B2: gh visible

        // epilogue pass 0 (nodes 0..3)
        #pragma unroll
        for (int mm = 0; mm < 2; ++mm) {
            const int node = 2 * mm + (lk >> 1);
            #pragma unroll
            for (int c = 0; c < 2; ++c) {
                const int col = cbase + c * 16 + ln;
                const float bgc = c ? bg1 : bg0;
                const float ghv = gh_s[node][col];
                float sum = 0.f;
                #pragma unroll
                for (int r = 0; r < 4; ++r) {
                    int row = mm * 16 + lk * 4 + r;
                    float g = sigmoidf_(aP[mm][c][r] + ghv + bgc);
                    sum += valid_s[row] * g * aM[mm][c][r];
                }
                sum += __shfl_xor(sum, 16);
                if ((l & 16) == 0) ncs[(2 * mm + (l >> 5)) * H + col] = bf(sum);
            }
        }

        // ================= PASS 1: m-tiles 2,3 =================
        #pragma unroll
        for (int mm = 0; mm < 2; ++mm)
            #pragma unroll
            for (int c = 0; c < 2; ++c) { aM[mm][c] = (f32x4)0.f; aP[mm][c] = (f32x4)0.f; }

        #pragma unroll
        for (int kk = 0; kk < 4; ++kk) {
            const int k0 = kk * 32 + lk * 8;
            bf16x8 am0, am1;
            {
                int row = 32 + ln;
                unsigned byte = (unsigned)(row * 256 + k0 * 2) ^ (unsigned)((row & 7) << 4);
                am0 = *(const bf16x8*)((const char*)hin_s + byte);
            }
            {
                int row = 48 + ln;
                unsigned byte = (unsigned)(row * 256 + k0 * 2) ^ (unsigned)((row & 7) << 4);
                am1 = *(const bf16x8*)((const char*)hin_s + byte);
            }
            #pragma unroll
            for (int c = 0; c < 2; ++c) {
                const int col = cbase + c * 16 + ln;
                bf16x8 bn = *(const bf16x8*)(WnB + col * H + k0);
                bf16x8 ba = *(const bf16x8*)(WgB + col * 2 * H + k0);
                aM[0][c] = MFMA16(am0, bn, aM[0][c]);
                aM[1][c] = MFMA16(am1, bn, aM[1][c]);
                aP[0][c] = MFMA16(am0, ba, aP[0][c]);
                aP[1][c] = MFMA16(am1, ba, aP[1][c]);
            }
        }

        // epilogue pass 1 (nodes 4..7)
        #pragma unroll
        for (int mm = 0; mm < 2; ++mm) {
            const int node = 4 + 2 * mm + (lk >> 1);
            #pragma unroll
            for (int c = 0; c < 2; ++c) {
                const int col = cbase + c * 16 + ln;
                const float bgc = c ? bg1 : bg0;
                const float ghv = gh_s[node][col];
                float sum = 0.f;
                #pragma unroll
                for (int r = 0; r < 4; ++r) {
                    int row = (2 + mm) * 16 + lk * 4 + r;
                    float g = sigmoidf_(aP[mm][c][r] + ghv + bgc);
                    sum += valid_s[row] * g * aM[mm][c][r];
                }
                sum += __shfl_xor(sum, 16);
                if ((l & 16) == 0) ncs[(4 + 2 * mm + (l >> 5)) * H + col] = bf(sum);
            }
        }
        __syncthreads();   // B3: ncs complete, all hin_s/gh_s reads done

        {   // coalesced bf16 nc write (ncs consumed into regs before store)
            int e = t * 4, node = e >> 7, col = e & 127;
            us4 v = *(const us4*)(ncs + e);
            *(us4*)(ncb + (size_t)(nb + node) * nc_stride + col) = v;
        }
        // no barrier: next stage writes hin_s/hs_s/valid_s whose reads all
        // completed before B3; ncs next written only after next B2.
    }
}

// ---------------------------------------------------------------------------
// LSTM via MFMA. 32 nodes/block, 512 threads (8 waves), low-register design:
// wave w owns z-cols [w*16, w*16+16) of ALL 4 gates -> acc = 2x4 f32x4.
// ---------------------------------------------------------------------------
__global__ __launch_bounds__(512, 4) void k_lstm_mfma(
    const float* __restrict__ x_g, const float* __restrict__ hself_g,
    const float* __restrict__ cself_g, const float* __restrict__ stat_g,
    const unsigned short* __restrict__ ncb, int nc_stride,
    const unsigned short* __restrict__ WpB, const float* __restrict__ bp,
    const float* __restrict__ lnw, const float* __restrict__ lnb,
    float* __restrict__ h_out, float* __restrict__ c_out)
{
    __shared__ char smem[MB_LSTM * CPAD * 2];      // 21KB
    unsigned short* comb = (unsigned short*)smem;  // [32][328] bf16
    float (*hpre)[132] = (float(*)[132])smem;      // union after GEMM

    const int t = threadIdx.x;
    const int nb = blockIdx.x * MB_LSTM;
    const int w = t >> 6, l = t & 63, ln = l & 15, lk = l >> 4;
    const int hcol = w * 16 + ln;

    // ---- stage comb' = [x | h_self | nc | static | 0] as bf16 ----
    if (t < 256) {  // x: 32*32 f32 = 256 float4
        int e = t * 4, row = e >> 5, col = e & 31;
        us4 pk = { 0, 0, 0, 0 };
        if (nb + row < NN) {
            float4 v = ((const float4*)(x_g + (size_t)nb * XD))[t];
            pk = us4{ bf(v.x), bf(v.y), bf(v.z), bf(v.w) };
        }
        *(us4*)(comb + row * CPAD + col) = pk;
    }
    #pragma unroll
    for (int i = 0; i < 2; ++i) {  // h_self: 32*128 f32 = 1024 float4
        int p4 = t + i * 512;
        int e = p4 * 4, row = e >> 7, col = 32 + (e & 127);
        us4 pk = { 0, 0, 0, 0 };
        if (nb + row < NN) {
            float4 v = ((const float4*)(hself_g + (size_t)nb * H))[p4];
            pk = us4{ bf(v.x), bf(v.y), bf(v.z), bf(v.w) };
        }
        *(us4*)(comb + row * CPAD + col) = pk;
    }
    #pragma unroll
    for (int i = 0; i < 2; ++i) {  // nc: 32*128 bf16 = 1024 us4
        int p4 = t + i * 512;
        int e = p4 * 4, row = e >> 7, col = e & 127;
        us4 v = { 0, 0, 0, 0 };
        if (nb + row < NN) v = *(const us4*)(ncb + (size_t)(nb + row) * nc_stride + col);
        *(us4*)(comb + row * CPAD + 160 + col) = v;
    }
    for (int i = t; i < MB_LSTM * SD; i += 512) {  // static: 32*27 f32
        int row = i / SD, col = i - row * SD;
        unsigned short v = 0;
        if (nb + row < NN) v = bf(stat_g[(size_t)(nb + row) * SD + col]);
        comb[row * CPAD + 288 + col] = v;
    }
    if (t < MB_LSTM * 5) {  // zero pad cols 315..319
        int row = t / 5, col = 315 + t % 5;
        comb[row * CPAD + col] = 0;
    }

    // ---- c_self prefetch (latency hides under GEMM) ----
    float cpre[8];
    #pragma unroll
    for (int m = 0; m < 2; ++m)
        #pragma unroll
        for (int r = 0; r < 4; ++r) {
            int node = m * 16 + lk * 4 + r;
            size_t n = (size_t)(nb + node);
            cpre[m * 4 + r] = (n < NN) ? cself_g[n * H + hcol] : 0.f;
        }
    __syncthreads();

    // ---- GEMM: z[32 x 512] = comb' @ W'^T ----
    f32x4 acc[2][4];  // [m-tile][gate]
    #pragma unroll
    for (int m = 0; m < 2; ++m)
        #pragma unroll
        for (int g = 0; g < 4; ++g) acc[m][g] = (f32x4)0.f;

    #pragma unroll
    for (int kk = 0; kk < 10; ++kk) {
        const int k0 = kk * 32 + lk * 8;
        bf16x8 a0 = *(const bf16x8*)(comb + ln * CPAD + k0);
        bf16x8 a1 = *(const bf16x8*)(comb + (16 + ln) * CPAD + k0);
        #pragma unroll
        for (int g = 0; g < 4; ++g) {
            bf16x8 b = *(const bf16x8*)(WpB + (size_t)(g * H + hcol) * CIN2 + k0);
            acc[0][g] = MFMA16(a0, b, acc[0][g]);
            acc[1][g] = MFMA16(a1, b, acc[1][g]);
        }
    }
    __syncthreads();  // comb reads done; hpre may overwrite

    // ---- LSTM elementwise ----
    {
        const float bi = bp[hcol], bff = bp[H + hcol];
        const float bo = bp[2 * H + hcol], bgg = bp[3 * H + hcol];
        #pragma unroll
        for (int m = 0; m < 2; ++m)
            #pragma unroll
            for (int r = 0; r < 4; ++r) {
                int node = m * 16 + lk * 4 + r;
                size_t n = (size_t)(nb + node);
                if (n < NN) {
                    float zi = acc[m][0][r] + bi;
                    float zf = acc[m][1][r] + bff;
                    float zo = acc[m][2][r] + bo;
                    float zg = acc[m][3][r] + bgg;
                    float cn = sigmoidf_(zf) * cpre[m * 4 + r] + sigmoidf_(zi) * tanhf_(zg);
                    c_out[n * H + hcol] = cn;
                    hpre[node][hcol] = sigmoidf_(zo) * tanhf_(cn);
                }
            }
    }
    __syncthreads();

    // ---- LayerNorm over H=128, 8 waves x 4 nodes ----
    #pragma unroll
    for (int jj = 0; jj < 4; ++jj) {
        const int j = w * 4 + jj;
        const size_t n = (size_t)(nb + j);
        if (n < NN) {
            float a = hpre[j][l];
            float b = hpre[j][64 + l];
            float s = a + b, q = a * a + b * b;
            #pragma unroll
            for (int off = 1; off < 64; off <<= 1) {
                s += __shfl_xor(s, off);
                q += __shfl_xor(q, off);
            }
            float mu = s * (1.0f / 128.0f);
            float var = q * (1.0f / 128.0f) - mu * mu;
            float rstd = rsqrtf(var + 1e-5f);
            h_out[n * H + l]      = (a - mu) * rstd * lnw[l] + lnb[l];
            h_out[n * H + 64 + l] = (b - mu) * rstd * lnw[64 + l] + lnb[64 + l];
        }
    }
}

// ---------------------------------------------------------------------------
// f32 fallback path — used only if ws is too small.
// ---------------------------------------------------------------------------
__global__ __launch_bounds__(256) void k_nb_f32(
    const float* __restrict__ hself_g, const float* __restrict__ hin_g,
    const unsigned char* __restrict__ valid_raw,
    const float* __restrict__ Wn, const float* __restrict__ Wg,
    const float* __restrict__ bg, float* __restrict__ nc)
{
    __shared__ float4 hin_s[8 * KI * (H / 4)];
    __shared__ float4 hs_s[8 * (H / 4)];
    __shared__ int flag8;
    const int t = threadIdx.x;
    const int nb = blockIdx.x * 8;
    {
        int loc = 0;
        if (t < 64) {
            #pragma unroll
            for (int i = 0; i < 16; ++i) loc |= valid_raw[4 * (t * 16 + i) + 1];
        }
        int any = __any(loc != 0);
        if (t == 0) flag8 = any;
    }
    const float4* src_hin = (const float4*)(hin_g + (size_t)nb * KI * H);
    #pragma unroll
    for (int i = 0; i < 8; ++i) hin_s[t + i * 256] = src_hin[t + i * 256];
    hs_s[t] = ((const float4*)(hself_g + (size_t)nb * H))[t];
    __syncthreads();
    const int o = t & 127, g = t >> 7;
    float msg[4][KI], gat[4][KI], gh[4];
    #pragma unroll
    for (int j = 0; j < 4; ++j) {
        gh[j] = 0.f;
        #pragma unroll
        for (int k = 0; k < KI; ++k) { msg[j][k] = 0.f; gat[j][k] = 0.f; }
    }
    const float4* Wn4 = (const float4*)(Wn + (size_t)o * H);
    const float4* Wg4a = (const float4*)(Wg + (size_t)o * 2 * H);
    const float4* Wg4b = (const float4*)(Wg + (size_t)o * 2 * H + H);
    for (int d4 = 0; d4 < H / 4; ++d4) {
        float4 wn = Wn4[d4], w0 = Wg4a[d4], w1 = Wg4b[d4];
        #pragma unroll
        for (int j = 0; j < 4; ++j) {
            const int node = g * 4 + j;
            gh[j] += dot4_(w1, hs_s[node * 32 + d4]);
            #pragma unroll
            for (int k = 0; k < KI; ++k) {
                float4 hv = hin_s[(node * KI + k) * 32 + d4];
                msg[j][k] += dot4_(wn, hv);
                gat[j][k] += dot4_(w0, hv);
            }
        }
    }
    const float bgo = bg[o];
    const unsigned int* valid32 = (const unsigned int*)valid_raw;
    const int f8 = flag8;
    #pragma unroll
    for (int j = 0; j < 4; ++j) {
        const int n = nb + g * 4 + j;
        float acc = 0.f;
        #pragma unroll
        for (int k = 0; k < KI; ++k) {
            bool v = f8 ? (valid_raw[n * KI + k] != 0) : (valid32[n * KI + k] != 0u);
            if (v) acc += sigmoidf_(gat[j][k] + gh[j] + bgo) * msg[j][k];
        }
        nc[(size_t)n * H + o] = acc;
    }
}

__global__ __launch_bounds__(256) void k_lstm_f32(
    const float* __restrict__ x_g, const float* __restrict__ hself_g,
    const float* __restrict__ cself_g, const float* __restrict__ stat_g,
    const float* __restrict__ nc,
    const float* __restrict__ Ws, const float* __restrict__ bs,
    const float* __restrict__ Wl, const float* __restrict__ bl,
    const float* __restrict__ lnw, const float* __restrict__ lnb,
    float* __restrict__ h_out, float* __restrict__ c_out)
{
    __shared__ float4 comb4[16 * (CIN / 4)];
    __shared__ float zsh[16 * ZOUT];
    __shared__ float stat_s[16 * SD];
    float* combf = (float*)comb4;
    const int t = threadIdx.x;
    const int nb = blockIdx.x * 16;
    #pragma unroll
    for (int i = 0; i < 2; ++i) {
        int idx = t + i * 256;
        combf[(idx >> 5) * CIN + (idx & 31)] = x_g[(size_t)nb * XD + idx];
    }
    #pragma unroll
    for (int i = 0; i < 8; ++i) {
        int idx = t + i * 256;
        combf[(idx >> 7) * CIN + 32 + (idx & 127)] = hself_g[(size_t)nb * H + idx];
    }
    #pragma unroll
    for (int i = 0; i < 8; ++i) {
        int idx = t + i * 256;
        combf[(idx >> 7) * CIN + 160 + (idx & 127)] = nc[(size_t)nb * H + idx];
    }
    stat_s[t] = stat_g[(size_t)nb * SD + t];
    if (t < 16 * SD - 256) stat_s[t + 256] = stat_g[(size_t)nb * SD + t + 256];
    __syncthreads();
    {
        const int o = t & 127, jg = t >> 7;
        #pragma unroll
        for (int jj = 0; jj < 8; ++jj) {
            const int j = jg * 8 + jj;
            float s = bs[o];
            #pragma unroll
            for (int c = 0; c < SD; ++c) s += Ws[o * SD + c] * stat_s[j * SD + c];
            combf[j * CIN + 288 + o] = s;
        }
    }
    __syncthreads();
    float acc0[16], acc1[16];
    #pragma unroll
    for (int j = 0; j < 16; ++j) { acc0[j] = 0.f; acc1[j] = 0.f; }
    const float4* W0 = (const float4*)(Wl + (size_t)t * CIN);
    const float4* W1 = (const float4*)(Wl + (size_t)(t + 256) * CIN);
    for (int d4 = 0; d4 < CIN / 4; ++d4) {
        float4 w0 = W0[d4], w1 = W1[d4];
        #pragma unroll
        for (int j = 0; j < 16; ++j) {
            float4 cv = comb4[j * (CIN / 4) + d4];
            acc0[j] += dot4_(w0, cv);
            acc1[j] += dot4_(w1, cv);
        }
    }
    const float bl0 = bl[t], bl1 = bl[t + 256];
    #pragma unroll
    for (int j = 0; j < 16; ++j) {
        zsh[j * ZOUT + t] = acc0[j] + bl0;
        zsh[j * ZOUT + 256 + t] = acc1[j] + bl1;
    }
    __syncthreads();
    {
        const int h = t & 127, jg = t >> 7;
        #pragma unroll
        for (int jj = 0; jj < 8; ++jj) {
            const int j = jg * 8 + jj;
            const size_t n = (size_t)(nb + j);
            float zi = zsh[j * ZOUT + h];
            float zf = zsh[j * ZOUT + 128 + h];
            float zo = zsh[j * ZOUT + 256 + h];
            float zg = zsh[j * ZOUT + 384 + h];
            float cn = sigmoidf_(zf) * cself_g[n * H + h] + sigmoidf_(zi) * tanhf(zg);
            c_out[n * H + h] = cn;
            zsh[j * ZOUT + h] = sigmoidf_(zo) * tanhf(cn);
        }
    }
    __syncthreads();
    {
        const int w = t >> 6, lane = t & 63;
        #pragma unroll
        for (int jj = 0; jj < 4; ++jj) {
            const int j = w * 4 + jj;
            const size_t n = (size_t)(nb + j);
            float a = zsh[j * ZOUT + lane];
            float b = zsh[j * ZOUT + 64 + lane];
            float s = a + b, q = a * a + b * b;
            #pragma unroll
            for (int off = 1; off < 64; off <<= 1) {
                s += __shfl_xor(s, off);
                q += __shfl_xor(q, off);
            }
            float mu = s * (1.0f / 128.0f);
            float var = q * (1.0f / 128.0f) - mu * mu;
            float rstd = rsqrtf(var + 1e-5f);
            h_out[n * H + lane] = (a - mu) * rstd * lnw[lane] + lnb[lane];
            h_out[n * H + 64 + lane] = (b - mu) * rstd * lnw[64 + lane] + lnb[64 + lane];
        }
    }
}

extern "C" void kernel_launch(void* const* d_in, const int* in_sizes, int n_in,
                              void* d_out, int out_size, void* d_ws, size_t ws_size,
                              hipStream_t stream) {
    const float* x      = (const float*)d_in[0];
    const float* h_self = (const float*)d_in[1];
    const float* c_self = (const float*)d_in[2];
    const float* h_inf  = (const float*)d_in[3];
    const unsigned char* valid = (const unsigned char*)d_in[4];
    const float* statp  = (const float*)d_in[5];
    const float* Wn     = (const float*)d_in[6];
    const float* Wg     = (const float*)d_in[7];
    const float* bg     = (const float*)d_in[8];
    const float* Ws     = (const float*)d_in[9];
    const float* bs     = (const float*)d_in[10];
    const float* Wl     = (const float*)d_in[11];
    const float* bl     = (const float*)d_in[12];
    const float* lnw    = (const float*)d_in[13];
    const float* lnb    = (const float*)d_in[14];

    float* h_out = (float*)d_out;
    float* c_out = h_out + (size_t)NN * H;

    const size_t W_BYTES = (size_t)512 * CIN2 * 2 + 16384 * 2 + 32768 * 2 + 512 * 4;
    const size_t NC_BYTES = (size_t)NN * H * 2;

    if (ws_size >= W_BYTES) {
        char* p = (char*)d_ws;
        unsigned short* WpB = (unsigned short*)p;           p += (size_t)512 * CIN2 * 2;
        unsigned short* WnB = (unsigned short*)p;           p += 16384 * 2;
        unsigned short* WgB = (unsigned short*)p;           p += 32768 * 2;
        float* bp = (float*)p;                              p += 512 * 4;

        unsigned short* ncb;
        int nc_stride;
        if (ws_size >= W_BYTES + NC_BYTES + 64) {
            ncb = (unsigned short*)p;
            nc_stride = H;
        } else {
            ncb = (unsigned short*)h_out;
            nc_stride = 256;
        }

        k_prep<<<576, 256, 0, stream>>>(Wn, Wg, Wl, bl, Ws, bs,
                                        WnB, WgB, WpB, bp);
        k_nb_mfma<<<GRID_NB, 256, 0, stream>>>(h_self, h_inf, valid, WnB, WgB, bg,
                                               ncb, nc_stride);
        k_lstm_mfma<<<(NN + MB_LSTM - 1) / MB_LSTM, 512, 0, stream>>>(
            x, h_self, c_self, statp, ncb, nc_stride, WpB, bp,
            lnw, lnb, h_out, c_out);
    } else {
        float* nc_buf = (ws_size >= (size_t)NN * H * sizeof(float))
                            ? (float*)d_ws : h_out;
        k_nb_f32<<<NN / 8, 256, 0, stream>>>(h_self, h_inf, valid, Wn, Wg, bg, nc_buf);
        k_lstm_f32<<<NN / 16, 256, 0, stream>>>(x, h_self, c_self, statp, nc_buf,
                                                Ws, bs, Wl, bl, lnw, lnb, h_out, c_out);
    }
}

// Round 7
// 245.893 us; speedup vs baseline: 1.0046x; 1.0046x over previous
//
#include <hip/hip_runtime.h>
#include <hip/hip_bf16.h>

#define NN 50000
#define KI 8
#define H 128
#define XD 32
#define SD 27
#define CIN 416      // original combined width
#define CIN2 320     // fused combined: x(32)|h(128)|nc(128)|static(27)|pad(5)
#define CPAD 328     // LDS row stride (shorts)
#define ZOUT 512
#define NTILE_NB (NN / KI)   // 6250 tiles of 8 nodes
#define MB_LSTM 32           // nodes per k_lstm block
#define GRID_NB 512

typedef __attribute__((ext_vector_type(8))) short bf16x8;
typedef __attribute__((ext_vector_type(4))) float f32x4;
typedef __attribute__((ext_vector_type(4))) unsigned short us4;
typedef __attribute__((ext_vector_type(8))) unsigned short us8;

#define MFMA16(a, b, c) __builtin_amdgcn_mfma_f32_16x16x32_bf16((a), (b), (c), 0, 0, 0)

typedef __attribute__((address_space(1))) const unsigned int gu32;
typedef __attribute__((address_space(3))) unsigned int lu32;

static __device__ __forceinline__ float sigmoidf_(float x) {
    return 1.0f / (1.0f + __expf(-x));
}
static __device__ __forceinline__ float tanhf_(float x) {
    return 1.0f - 2.0f / (__expf(2.0f * x) + 1.0f);
}
static __device__ __forceinline__ unsigned short bf(float f) {
    __hip_bfloat16 h = __float2bfloat16(f);
    return __builtin_bit_cast(unsigned short, h);
}
static __device__ __forceinline__ float dot4_(float4 a, float4 b) {
    return a.x * b.x + a.y * b.y + a.z * b.z + a.w * b.w;
}

// ---------------------------------------------------------------------------
// Prep: bf16 weights + fused LSTM weight W' and bias b'.
// ---------------------------------------------------------------------------
__global__ __launch_bounds__(256) void k_prep(
    const float* __restrict__ Wn, const float* __restrict__ Wg,
    const float* __restrict__ Wl, const float* __restrict__ bl,
    const float* __restrict__ Ws, const float* __restrict__ bs,
    unsigned short* __restrict__ WnB, unsigned short* __restrict__ WgB,
    unsigned short* __restrict__ WpB, float* __restrict__ bp)
{
    const int b = blockIdx.x, t = threadIdx.x;
    if (b < 512) {
        const float* wr = Wl + (size_t)b * CIN;
        unsigned short* out = WpB + (size_t)b * CIN2;
        for (int c = t; c < CIN2; c += 256) {
            float v;
            if (c < 288) v = wr[c];
            else if (c < 288 + SD) {
                int s = c - 288;
                float acc = 0.f;
                for (int j = 0; j < H; ++j) acc += wr[288 + j] * Ws[j * SD + s];
                v = acc;
            } else v = 0.f;
            out[c] = bf(v);
        }
        if (t == 0) {
            float acc = bl[b];
            for (int j = 0; j < H; ++j) acc += wr[288 + j] * bs[j];
            bp[b] = acc;
        }
    } else {
        int idx = (b - 512) * 256 + t;
        for (int r = idx; r < 49152; r += 16384) {
            if (r < 16384) WnB[r] = bf(Wn[r]);
            else WgB[r - 16384] = bf(Wg[r - 16384]);
        }
    }
}

// ---------------------------------------------------------------------------
// Neighbor context v3: async global_load_lds double-buffer (m97 pattern).
//  - f32 tiles DMA'd HBM->LDS with pre-swizzled per-lane SOURCE addresses
//    (dest linear); reads use the same (row&7)<<4 XOR -> both-sides swizzle.
//  - bf16 conversion folded into fragment reads (cvt_pk on the fly).
//  - one __syncthreads per tile (its implicit vmcnt drain = DMA completion);
//    gh exchange intra-wave; nc written straight to global.
//  - 256 threads (4 waves); wave w owns h-cols [w*32, w*32+32).
// ---------------------------------------------------------------------------
__global__ __launch_bounds__(256, 2) void k_nb_mfma(
    const float* __restrict__ hself_g, const float* __restrict__ hin_g,
    const unsigned char* __restrict__ valid_raw,
    const unsigned short* __restrict__ WnB, const unsigned short* __restrict__ WgB,
    const float* __restrict__ bg,
    unsigned short* __restrict__ ncb, int nc_stride)
{
    __shared__ __align__(16) float hinf[2][64 * 128];  // 32KB x2, swizzled f32
    __shared__ __align__(16) float hsf[2][8 * 128];    // 4KB x2, swizzled f32
    __shared__ float gh_s[8][128];                     // 4KB

    const int t = threadIdx.x;
    const int w = t >> 6, l = t & 63;
    const int ln = l & 15, lk = l >> 4;
    const int wb = __builtin_amdgcn_readfirstlane(w);

    // detect inflow_valid element width (bool8 vs 4-byte) — uniform, once
    int det = 0;
    #pragma unroll
    for (int i = 0; i < 64; ++i) det |= valid_raw[4 * i + 1];
    const bool f8 = (det != 0);

    const int cbase = w * 32;
    const float bg0 = bg[cbase + ln];
    const float bg1 = bg[cbase + 16 + ln];

    // per-lane inverse-swizzled global float-offsets for the DMA
    int hin_off[8];
    #pragma unroll
    for (int i = 0; i < 8; ++i) {
        int D = ((i * 4 + w) * 64 + l) * 16;             // dest byte in 32KB buf
        int row = D >> 9;                                 // 512B per row
        int inner = (D & 511) ^ ((row & 7) << 4);         // undo read-side XOR
        hin_off[i] = row * 128 + (inner >> 2);
    }
    int hs_off;
    {
        int D = (w * 64 + l) * 16;                        // dest byte in 4KB buf
        int row = D >> 9;
        int inner = (D & 511) ^ ((row & 7) << 4);
        hs_off = row * 128 + (inner >> 2);
    }

    // prologue: DMA tile(blockIdx.x) into buffer 0
    {
        const float* hb = hin_g + (size_t)blockIdx.x * 8 * KI * H;
        #pragma unroll
        for (int i = 0; i < 8; ++i)
            __builtin_amdgcn_global_load_lds((gu32*)(hb + hin_off[i]),
                (lu32*)&hinf[0][(i * 4 + wb) * 256], 16, 0, 0);
        __builtin_amdgcn_global_load_lds(
            (gu32*)(hself_g + (size_t)blockIdx.x * 8 * H + hs_off),
            (lu32*)&hsf[0][wb * 256], 16, 0, 0);
    }
    __syncthreads();   // implicit vmcnt(0) drain: buffer 0 ready

    int cur = 0;
    for (int tile = blockIdx.x; tile < NTILE_NB; tile += GRID_NB) {
        const int nb = tile * 8;

        // ---- issue DMA for tile t+1 into buf[cur^1] (completes by barrier) ----
        const int next = tile + GRID_NB;
        if (next < NTILE_NB) {
            const float* hb = hin_g + (size_t)next * 8 * KI * H;
            #pragma unroll
            for (int i = 0; i < 8; ++i)
                __builtin_amdgcn_global_load_lds((gu32*)(hb + hin_off[i]),
                    (lu32*)&hinf[cur ^ 1][(i * 4 + wb) * 256], 16, 0, 0);
            __builtin_amdgcn_global_load_lds(
                (gu32*)(hself_g + (size_t)next * 8 * H + hs_off),
                (lu32*)&hsf[cur ^ 1][wb * 256], 16, 0, 0);
        }

        // ---- valid flags for CURRENT tile (broadcast L2 reads, used late) ----
        uint4 rv[4];
        if (f8) {
            const unsigned* vb = (const unsigned*)(valid_raw + (size_t)nb * KI);
            #pragma unroll
            for (int m = 0; m < 4; ++m) rv[m].x = vb[lk + 4 * m];
        } else {
            const uint4* vb = (const uint4*)((const unsigned*)valid_raw + (size_t)nb * KI);
            #pragma unroll
            for (int m = 0; m < 4; ++m) rv[m] = vb[lk + 4 * m];
        }

        // ---- MFMA over buf[cur]: fragments read f32-swizzled, cvt to bf16 ----
        const float* hbuf = hinf[cur];
        const float* sbuf = hsf[cur];

        f32x4 aM[4][2], aP[4][2], aG[2];
        #pragma unroll
        for (int m = 0; m < 4; ++m)
            #pragma unroll
            for (int c = 0; c < 2; ++c) { aM[m][c] = (f32x4)0.f; aP[m][c] = (f32x4)0.f; }
        aG[0] = (f32x4)0.f; aG[1] = (f32x4)0.f;

        #pragma unroll
        for (int kk = 0; kk < 4; ++kk) {
            const int k0 = kk * 32 + lk * 8;
            bf16x8 am[4], ah;
            #pragma unroll
            for (int m = 0; m < 4; ++m) {
                const int row = m * 16 + ln;
                const unsigned x = (unsigned)((row & 7) << 4);
                const float4 q0 = *(const float4*)((const char*)hbuf + row * 512 + ((k0 * 4) ^ x));
                const float4 q1 = *(const float4*)((const char*)hbuf + row * 512 + ((k0 * 4 + 16) ^ x));
                us8 pk = { bf(q0.x), bf(q0.y), bf(q0.z), bf(q0.w),
                           bf(q1.x), bf(q1.y), bf(q1.z), bf(q1.w) };
                am[m] = __builtin_bit_cast(bf16x8, pk);
            }
            {
                const int row = ln & 7;
                const unsigned x = (unsigned)(row << 4);
                const float4 q0 = *(const float4*)((const char*)sbuf + row * 512 + ((k0 * 4) ^ x));
                const float4 q1 = *(const float4*)((const char*)sbuf + row * 512 + ((k0 * 4 + 16) ^ x));
                us8 pk = { bf(q0.x), bf(q0.y), bf(q0.z), bf(q0.w),
                           bf(q1.x), bf(q1.y), bf(q1.z), bf(q1.w) };
                ah = __builtin_bit_cast(bf16x8, pk);
            }
            #pragma unroll
            for (int c = 0; c < 2; ++c) {
                const int col = cbase + c * 16 + ln;
                const bf16x8 bn = *(const bf16x8*)(WnB + col * H + k0);
                const bf16x8 ba = *(const bf16x8*)(WgB + col * 2 * H + k0);
                const bf16x8 bb = *(const bf16x8*)(WgB + col * 2 * H + H + k0);
                #pragma unroll
                for (int m = 0; m < 4; ++m) {
                    aM[m][c] = MFMA16(am[m], bn, aM[m][c]);
                    aP[m][c] = MFMA16(am[m], ba, aP[m][c]);
                }
                aG[c] = MFMA16(ah, bb, aG[c]);
            }
        }

        // ---- gh to LDS (intra-wave exchange: same wave writes/reads its cols) ----
        #pragma unroll
        for (int c = 0; c < 2; ++c)
            #pragma unroll
            for (int r = 0; r < 4; ++r) {
                const int row = lk * 4 + r;
                if (row < 8) gh_s[row][cbase + c * 16 + ln] = aG[c][r];
            }

        // ---- epilogue: gate, mask, k-sum, direct global nc write ----
        #pragma unroll
        for (int m = 0; m < 4; ++m) {
            const int node = 2 * m + (lk >> 1);
            const uint4 rvm = rv[m];
            #pragma unroll
            for (int c = 0; c < 2; ++c) {
                const int col = cbase + c * 16 + ln;
                const float bgc = c ? bg1 : bg0;
                const float ghv = gh_s[node][col];
                float sum = 0.f;
                #pragma unroll
                for (int r = 0; r < 4; ++r) {
                    const unsigned uw = (r == 0) ? rvm.x : (r == 1) ? rvm.y
                                      : (r == 2) ? rvm.z : rvm.w;
                    const bool vf = f8 ? (((rvm.x >> (8 * r)) & 0xffu) != 0u)
                                       : (uw != 0u);
                    const float g = sigmoidf_(aP[m][c][r] + ghv + bgc);
                    sum += vf ? g * aM[m][c][r] : 0.f;
                }
                sum += __shfl_xor(sum, 16);
                if ((l & 16) == 0) {
                    const int node_o = 2 * m + (l >> 5);
                    ncb[(size_t)(nb + node_o) * nc_stride + col] = bf(sum);
                }
            }
        }

        __syncthreads();   // implicit vmcnt(0): next tile's DMA landed; all
                           // waves done reading buf[cur] before its reuse
        cur ^= 1;
    }
}

// ---------------------------------------------------------------------------
// LSTM via MFMA. 32 nodes/block, 512 threads (8 waves), low-register design.
// ---------------------------------------------------------------------------
__global__ __launch_bounds__(512, 4) void k_lstm_mfma(
    const float* __restrict__ x_g, const float* __restrict__ hself_g,
    const float* __restrict__ cself_g, const float* __restrict__ stat_g,
    const unsigned short* __restrict__ ncb, int nc_stride,
    const unsigned short* __restrict__ WpB, const float* __restrict__ bp,
    const float* __restrict__ lnw, const float* __restrict__ lnb,
    float* __restrict__ h_out, float* __restrict__ c_out)
{
    __shared__ char smem[MB_LSTM * CPAD * 2];      // 21KB
    unsigned short* comb = (unsigned short*)smem;  // [32][328] bf16
    float (*hpre)[132] = (float(*)[132])smem;      // union after GEMM

    const int t = threadIdx.x;
    const int nb = blockIdx.x * MB_LSTM;
    const int w = t >> 6, l = t & 63, ln = l & 15, lk = l >> 4;
    const int hcol = w * 16 + ln;

    if (t < 256) {  // x
        int e = t * 4, row = e >> 5, col = e & 31;
        us4 pk = { 0, 0, 0, 0 };
        if (nb + row < NN) {
            float4 v = ((const float4*)(x_g + (size_t)nb * XD))[t];
            pk = us4{ bf(v.x), bf(v.y), bf(v.z), bf(v.w) };
        }
        *(us4*)(comb + row * CPAD + col) = pk;
    }
    #pragma unroll
    for (int i = 0; i < 2; ++i) {  // h_self
        int p4 = t + i * 512;
        int e = p4 * 4, row = e >> 7, col = 32 + (e & 127);
        us4 pk = { 0, 0, 0, 0 };
        if (nb + row < NN) {
            float4 v = ((const float4*)(hself_g + (size_t)nb * H))[p4];
            pk = us4{ bf(v.x), bf(v.y), bf(v.z), bf(v.w) };
        }
        *(us4*)(comb + row * CPAD + col) = pk;
    }
    #pragma unroll
    for (int i = 0; i < 2; ++i) {  // nc (already bf16)
        int p4 = t + i * 512;
        int e = p4 * 4, row = e >> 7, col = e & 127;
        us4 v = { 0, 0, 0, 0 };
        if (nb + row < NN) v = *(const us4*)(ncb + (size_t)(nb + row) * nc_stride + col);
        *(us4*)(comb + row * CPAD + 160 + col) = v;
    }
    for (int i = t; i < MB_LSTM * SD; i += 512) {  // static
        int row = i / SD, col = i - row * SD;
        unsigned short v = 0;
        if (nb + row < NN) v = bf(stat_g[(size_t)(nb + row) * SD + col]);
        comb[row * CPAD + 288 + col] = v;
    }
    if (t < MB_LSTM * 5) {  // zero pad
        int row = t / 5, col = 315 + t % 5;
        comb[row * CPAD + col] = 0;
    }

    float cpre[8];
    #pragma unroll
    for (int m = 0; m < 2; ++m)
        #pragma unroll
        for (int r = 0; r < 4; ++r) {
            int node = m * 16 + lk * 4 + r;
            size_t n = (size_t)(nb + node);
            cpre[m * 4 + r] = (n < NN) ? cself_g[n * H + hcol] : 0.f;
        }
    __syncthreads();

    f32x4 acc[2][4];
    #pragma unroll
    for (int m = 0; m < 2; ++m)
        #pragma unroll
        for (int g = 0; g < 4; ++g) acc[m][g] = (f32x4)0.f;

    #pragma unroll
    for (int kk = 0; kk < 10; ++kk) {
        const int k0 = kk * 32 + lk * 8;
        bf16x8 a0 = *(const bf16x8*)(comb + ln * CPAD + k0);
        bf16x8 a1 = *(const bf16x8*)(comb + (16 + ln) * CPAD + k0);
        #pragma unroll
        for (int g = 0; g < 4; ++g) {
            bf16x8 b = *(const bf16x8*)(WpB + (size_t)(g * H + hcol) * CIN2 + k0);
            acc[0][g] = MFMA16(a0, b, acc[0][g]);
            acc[1][g] = MFMA16(a1, b, acc[1][g]);
        }
    }
    __syncthreads();

    {
        const float bi = bp[hcol], bff = bp[H + hcol];
        const float bo = bp[2 * H + hcol], bgg = bp[3 * H + hcol];
        #pragma unroll
        for (int m = 0; m < 2; ++m)
            #pragma unroll
            for (int r = 0; r < 4; ++r) {
                int node = m * 16 + lk * 4 + r;
                size_t n = (size_t)(nb + node);
                if (n < NN) {
                    float zi = acc[m][0][r] + bi;
                    float zf = acc[m][1][r] + bff;
                    float zo = acc[m][2][r] + bo;
                    float zg = acc[m][3][r] + bgg;
                    float cn = sigmoidf_(zf) * cpre[m * 4 + r] + sigmoidf_(zi) * tanhf_(zg);
                    c_out[n * H + hcol] = cn;
                    hpre[node][hcol] = sigmoidf_(zo) * tanhf_(cn);
                }
            }
    }
    __syncthreads();

    #pragma unroll
    for (int jj = 0; jj < 4; ++jj) {
        const int j = w * 4 + jj;
        const size_t n = (size_t)(nb + j);
        if (n < NN) {
            float a = hpre[j][l];
            float b = hpre[j][64 + l];
            float s = a + b, q = a * a + b * b;
            #pragma unroll
            for (int off = 1; off < 64; off <<= 1) {
                s += __shfl_xor(s, off);
                q += __shfl_xor(q, off);
            }
            float mu = s * (1.0f / 128.0f);
            float var = q * (1.0f / 128.0f) - mu * mu;
            float rstd = rsqrtf(var + 1e-5f);
            h_out[n * H + l]      = (a - mu) * rstd * lnw[l] + lnb[l];
            h_out[n * H + 64 + l] = (b - mu) * rstd * lnw[64 + l] + lnb[64 + l];
        }
    }
}

// ---------------------------------------------------------------------------
// f32 fallback path — used only if ws is too small.
// ---------------------------------------------------------------------------
__global__ __launch_bounds__(256) void k_nb_f32(
    const float* __restrict__ hself_g, const float* __restrict__ hin_g,
    const unsigned char* __restrict__ valid_raw,
    const float* __restrict__ Wn, const float* __restrict__ Wg,
    const float* __restrict__ bg, float* __restrict__ nc)
{
    __shared__ float4 hin_s[8 * KI * (H / 4)];
    __shared__ float4 hs_s[8 * (H / 4)];
    __shared__ int flag8;
    const int t = threadIdx.x;
    const int nb = blockIdx.x * 8;
    {
        int loc = 0;
        if (t < 64) {
            #pragma unroll
            for (int i = 0; i < 16; ++i) loc |= valid_raw[4 * (t * 16 + i) + 1];
        }
        int any = __any(loc != 0);
        if (t == 0) flag8 = any;
    }
    const float4* src_hin = (const float4*)(hin_g + (size_t)nb * KI * H);
    #pragma unroll
    for (int i = 0; i < 8; ++i) hin_s[t + i * 256] = src_hin[t + i * 256];
    hs_s[t] = ((const float4*)(hself_g + (size_t)nb * H))[t];
    __syncthreads();
    const int o = t & 127, g = t >> 7;
    float msg[4][KI], gat[4][KI], gh[4];
    #pragma unroll
    for (int j = 0; j < 4; ++j) {
        gh[j] = 0.f;
        #pragma unroll
        for (int k = 0; k < KI; ++k) { msg[j][k] = 0.f; gat[j][k] = 0.f; }
    }
    const float4* Wn4 = (const float4*)(Wn + (size_t)o * H);
    const float4* Wg4a = (const float4*)(Wg + (size_t)o * 2 * H);
    const float4* Wg4b = (const float4*)(Wg + (size_t)o * 2 * H + H);
    for (int d4 = 0; d4 < H / 4; ++d4) {
        float4 wn = Wn4[d4], w0 = Wg4a[d4], w1 = Wg4b[d4];
        #pragma unroll
        for (int j = 0; j < 4; ++j) {
            const int node = g * 4 + j;
            gh[j] += dot4_(w1, hs_s[node * 32 + d4]);
            #pragma unroll
            for (int k = 0; k < KI; ++k) {
                float4 hv = hin_s[(node * KI + k) * 32 + d4];
                msg[j][k] += dot4_(wn, hv);
                gat[j][k] += dot4_(w0, hv);
            }
        }
    }
    const float bgo = bg[o];
    const unsigned int* valid32 = (const unsigned int*)valid_raw;
    const int f8 = flag8;
    #pragma unroll
    for (int j = 0; j < 4; ++j) {
        const int n = nb + g * 4 + j;
        float acc = 0.f;
        #pragma unroll
        for (int k = 0; k < KI; ++k) {
            bool v = f8 ? (valid_raw[n * KI + k] != 0) : (valid32[n * KI + k] != 0u);
            if (v) acc += sigmoidf_(gat[j][k] + gh[j] + bgo) * msg[j][k];
        }
        nc[(size_t)n * H + o] = acc;
    }
}

__global__ __launch_bounds__(256) void k_lstm_f32(
    const float* __restrict__ x_g, const float* __restrict__ hself_g,
    const float* __restrict__ cself_g, const float* __restrict__ stat_g,
    const float* __restrict__ nc,
    const float* __restrict__ Ws, const float* __restrict__ bs,
    const float* __restrict__ Wl, const float* __restrict__ bl,
    const float* __restrict__ lnw, const float* __restrict__ lnb,
    float* __restrict__ h_out, float* __restrict__ c_out)
{
    __shared__ float4 comb4[16 * (CIN / 4)];
    __shared__ float zsh[16 * ZOUT];
    __shared__ float stat_s[16 * SD];
    float* combf = (float*)comb4;
    const int t = threadIdx.x;
    const int nb = blockIdx.x * 16;
    #pragma unroll
    for (int i = 0; i < 2; ++i) {
        int idx = t + i * 256;
        combf[(idx >> 5) * CIN + (idx & 31)] = x_g[(size_t)nb * XD + idx];
    }
    #pragma unroll
    for (int i = 0; i < 8; ++i) {
        int idx = t + i * 256;
        combf[(idx >> 7) * CIN + 32 + (idx & 127)] = hself_g[(size_t)nb * H + idx];
    }
    #pragma unroll
    for (int i = 0; i < 8; ++i) {
        int idx = t + i * 256;
        combf[(idx >> 7) * CIN + 160 + (idx & 127)] = nc[(size_t)nb * H + idx];
    }
    stat_s[t] = stat_g[(size_t)nb * SD + t];
    if (t < 16 * SD - 256) stat_s[t + 256] = stat_g[(size_t)nb * SD + t + 256];
    __syncthreads();
    {
        const int o = t & 127, jg = t >> 7;
        #pragma unroll
        for (int jj = 0; jj < 8; ++jj) {
            const int j = jg * 8 + jj;
            float s = bs[o];
            #pragma unroll
            for (int c = 0; c < SD; ++c) s += Ws[o * SD + c] * stat_s[j * SD + c];
            combf[j * CIN + 288 + o] = s;
        }
    }
    __syncthreads();
    float acc0[16], acc1[16];
    #pragma unroll
    for (int j = 0; j < 16; ++j) { acc0[j] = 0.f; acc1[j] = 0.f; }
    const float4* W0 = (const float4*)(Wl + (size_t)t * CIN);
    const float4* W1 = (const float4*)(Wl + (size_t)(t + 256) * CIN);
    for (int d4 = 0; d4 < CIN / 4; ++d4) {
        float4 w0 = W0[d4], w1 = W1[d4];
        #pragma unroll
        for (int j = 0; j < 16; ++j) {
            float4 cv = comb4[j * (CIN / 4) + d4];
            acc0[j] += dot4_(w0, cv);
            acc1[j] += dot4_(w1, cv);
        }
    }
    const float bl0 = bl[t], bl1 = bl[t + 256];
    #pragma unroll
    for (int j = 0; j < 16; ++j) {
        zsh[j * ZOUT + t] = acc0[j] + bl0;
        zsh[j * ZOUT + 256 + t] = acc1[j] + bl1;
    }
    __syncthreads();
    {
        const int h = t & 127, jg = t >> 7;
        #pragma unroll
        for (int jj = 0; jj < 8; ++jj) {
            const int j = jg * 8 + jj;
            const size_t n = (size_t)(nb + j);
            float zi = zsh[j * ZOUT + h];
            float zf = zsh[j * ZOUT + 128 + h];
            float zo = zsh[j * ZOUT + 256 + h];
            float zg = zsh[j * ZOUT + 384 + h];
            float cn = sigmoidf_(zf) * cself_g[n * H + h] + sigmoidf_(zi) * tanhf(zg);
            c_out[n * H + h] = cn;
            zsh[j * ZOUT + h] = sigmoidf_(zo) * tanhf(cn);
        }
    }
    __syncthreads();
    {
        const int w = t >> 6, lane = t & 63;
        #pragma unroll
        for (int jj = 0; jj < 4; ++jj) {
            const int j = w * 4 + jj;
            const size_t n = (size_t)(nb + j);
            float a = zsh[j * ZOUT + lane];
            float b = zsh[j * ZOUT + 64 + lane];
            float s = a + b, q = a * a + b * b;
            #pragma unroll
            for (int off = 1; off < 64; off <<= 1) {
                s += __shfl_xor(s, off);
                q += __shfl_xor(q, off);
            }
            float mu = s * (1.0f / 128.0f);
            float var = q * (1.0f / 128.0f) - mu * mu;
            float rstd = rsqrtf(var + 1e-5f);
            h_out[n * H + lane] = (a - mu) * rstd * lnw[lane] + lnb[lane];
            h_out[n * H + 64 + lane] = (b - mu) * rstd * lnw[64 + lane] + lnb[64 + lane];
        }
    }
}

extern "C" void kernel_launch(void* const* d_in, const int* in_sizes, int n_in,
                              void* d_out, int out_size, void* d_ws, size_t ws_size,
                              hipStream_t stream) {
    const float* x      = (const float*)d_in[0];
    const float* h_self = (const float*)d_in[1];
    const float* c_self = (const float*)d_in[2];
    const float* h_inf  = (const float*)d_in[3];
    const unsigned char* valid = (const unsigned char*)d_in[4];
    const float* statp  = (const float*)d_in[5];
    const float* Wn     = (const float*)d_in[6];
    const float* Wg     = (const float*)d_in[7];
    const float* bg     = (const float*)d_in[8];
    const float* Ws     = (const float*)d_in[9];
    const float* bs     = (const float*)d_in[10];
    const float* Wl     = (const float*)d_in[11];
    const float* bl     = (const float*)d_in[12];
    const float* lnw    = (const float*)d_in[13];
    const float* lnb    = (const float*)d_in[14];

    float* h_out = (float*)d_out;
    float* c_out = h_out + (size_t)NN * H;

    const size_t W_BYTES = (size_t)512 * CIN2 * 2 + 16384 * 2 + 32768 * 2 + 512 * 4;
    const size_t NC_BYTES = (size_t)NN * H * 2;

    if (ws_size >= W_BYTES) {
        char* p = (char*)d_ws;
        unsigned short* WpB = (unsigned short*)p;           p += (size_t)512 * CIN2 * 2;
        unsigned short* WnB = (unsigned short*)p;           p += 16384 * 2;
        unsigned short* WgB = (unsigned short*)p;           p += 32768 * 2;
        float* bp = (float*)p;                              p += 512 * 4;

        unsigned short* ncb;
        int nc_stride;
        if (ws_size >= W_BYTES + NC_BYTES + 64) {
            ncb = (unsigned short*)p;
            nc_stride = H;
        } else {
            ncb = (unsigned short*)h_out;
            nc_stride = 256;
        }

        k_prep<<<576, 256, 0, stream>>>(Wn, Wg, Wl, bl, Ws, bs,
                                        WnB, WgB, WpB, bp);
        k_nb_mfma<<<GRID_NB, 256, 0, stream>>>(h_self, h_inf, valid, WnB, WgB, bg,
                                               ncb, nc_stride);
        k_lstm_mfma<<<(NN + MB_LSTM - 1) / MB_LSTM, 512, 0, stream>>>(
            x, h_self, c_self, statp, ncb, nc_stride, WpB, bp,
            lnw, lnb, h_out, c_out);
    } else {
        float* nc_buf = (ws_size >= (size_t)NN * H * sizeof(float))
                            ? (float*)d_ws : h_out;
        k_nb_f32<<<NN / 8, 256, 0, stream>>>(h_self, h_inf, valid, Wn, Wg, bg, nc_buf);
        k_lstm_f32<<<NN / 16, 256, 0, stream>>>(x, h_self, c_self, statp, nc_buf,
                                                Ws, bs, Wl, bl, lnw, lnb, h_out, c_out);
    }
}

// Round 8
// 184.803 us; speedup vs baseline: 1.3367x; 1.3306x over previous
//
#include <hip/hip_runtime.h>
#include <hip/hip_bf16.h>

#define NN 50000
#define KI 8
#define H 128
#define XD 32
#define SD 27
#define CIN 416      // original combined width
#define CIN2 320     // fused combined: x(32)|h(128)|nc(128)|static(27)|pad(5)
#define CPAD 328     // LDS row stride (shorts)
#define ZOUT 512
#define NTILE_NB (NN / KI)   // 6250 tiles of 8 nodes
#define MB_LSTM 32           // nodes per k_lstm block
#define GRID_NB 1024         // 4 blocks/CU resident (VGPR 128, LDS 25KB)

typedef __attribute__((ext_vector_type(8))) short bf16x8;
typedef __attribute__((ext_vector_type(4))) float f32x4;
typedef __attribute__((ext_vector_type(4))) unsigned short us4;

#define MFMA16(a, b, c) __builtin_amdgcn_mfma_f32_16x16x32_bf16((a), (b), (c), 0, 0, 0)

static __device__ __forceinline__ float sigmoidf_(float x) {
    return 1.0f / (1.0f + __expf(-x));
}
// fast tanh, saturation-safe: 1 - 2/(e^{2x}+1)
static __device__ __forceinline__ float tanhf_(float x) {
    return 1.0f - 2.0f / (__expf(2.0f * x) + 1.0f);
}
// f32 -> bf16 via HW cvt (compiler emits v_cvt_pk_bf16_f32 for pairs)
static __device__ __forceinline__ unsigned short bf(float f) {
    __hip_bfloat16 h = __float2bfloat16(f);
    return __builtin_bit_cast(unsigned short, h);
}
static __device__ __forceinline__ float dot4_(float4 a, float4 b) {
    return a.x * b.x + a.y * b.y + a.z * b.z + a.w * b.w;
}

// ---------------------------------------------------------------------------
// Prep: bf16 weights + fused LSTM weight W' and bias b'.
// ---------------------------------------------------------------------------
__global__ __launch_bounds__(256) void k_prep(
    const float* __restrict__ Wn, const float* __restrict__ Wg,
    const float* __restrict__ Wl, const float* __restrict__ bl,
    const float* __restrict__ Ws, const float* __restrict__ bs,
    unsigned short* __restrict__ WnB, unsigned short* __restrict__ WgB,
    unsigned short* __restrict__ WpB, float* __restrict__ bp)
{
    const int b = blockIdx.x, t = threadIdx.x;
    if (b < 512) {
        const float* wr = Wl + (size_t)b * CIN;
        unsigned short* out = WpB + (size_t)b * CIN2;
        for (int c = t; c < CIN2; c += 256) {
            float v;
            if (c < 288) v = wr[c];
            else if (c < 288 + SD) {
                int s = c - 288;
                float acc = 0.f;
                for (int j = 0; j < H; ++j) acc += wr[288 + j] * Ws[j * SD + s];
                v = acc;
            } else v = 0.f;
            out[c] = bf(v);
        }
        if (t == 0) {
            float acc = bl[b];
            for (int j = 0; j < H; ++j) acc += wr[288 + j] * bs[j];
            bp[b] = acc;
        }
    } else {
        int idx = (b - 512) * 256 + t;
        for (int r = idx; r < 49152; r += 16384) {
            if (r < 16384) WnB[r] = bf(Wn[r]);
            else WgB[r - 16384] = bf(Wg[r - 16384]);
        }
    }
}

// ---------------------------------------------------------------------------
// Neighbor context (R4 structure + grid for 4 blocks/CU):
//  - persistent weight registers (Wn/Wg fragments, 96 VGPR);
//  - bf16 reg-staged XOR-swizzled LDS tiles (25KB);
//  - 3 barriers/tile; ncs-staged coalesced nc write;
//  - grid-stride over 6250 8-node tiles, 1024 blocks.
// ---------------------------------------------------------------------------
__global__ __launch_bounds__(256, 2) void k_nb_mfma(
    const float* __restrict__ hself_g, const float* __restrict__ hin_g,
    const unsigned char* __restrict__ valid_raw,
    const unsigned short* __restrict__ WnB, const unsigned short* __restrict__ WgB,
    const float* __restrict__ bg,
    unsigned short* __restrict__ ncb, int nc_stride)
{
    __shared__ unsigned short hin_s[64 * 128];  // XOR-swizzled, 16KB
    __shared__ unsigned short hs_s[8 * 128];    // XOR-swizzled, 2KB
    __shared__ float gh_s[8][128];              // 4KB
    __shared__ unsigned short ncs[8 * 128];     // 2KB
    __shared__ float valid_s[64];

    const int t = threadIdx.x;
    const int w = t >> 6, l = t & 63;
    const int ln = l & 15, lk = l >> 4;

    // detect inflow_valid element width (bool8 vs 4-byte) — uniform, once
    int det = 0;
    #pragma unroll
    for (int i = 0; i < 64; ++i) det |= valid_raw[4 * i + 1];
    const bool f8 = (det != 0);

    // ---- persistent B fragments: Wn, Wg_a (inflow), Wg_b (h_self) ----
    bf16x8 Bn[2][4], Ba[2][4], Bb[2][4];
    const int cbase = w * 32;
    #pragma unroll
    for (int c = 0; c < 2; ++c) {
        const int col = cbase + c * 16 + ln;
        #pragma unroll
        for (int kk = 0; kk < 4; ++kk) {
            const int k0 = kk * 32 + lk * 8;
            Bn[c][kk] = *(const bf16x8*)(WnB + col * H + k0);
            Ba[c][kk] = *(const bf16x8*)(WgB + col * 2 * H + k0);
            Bb[c][kk] = *(const bf16x8*)(WgB + col * 2 * H + H + k0);
        }
    }
    const float bg0 = bg[cbase + ln];
    const float bg1 = bg[cbase + 16 + ln];

    for (int tile = blockIdx.x; tile < NTILE_NB; tile += GRID_NB) {
        const int nb = tile * 8;

        if (t < 64)
            valid_s[t] = (f8 ? (valid_raw[(size_t)nb * KI + t] != 0)
                             : (((const unsigned int*)valid_raw)[(size_t)nb * KI + t] != 0u))
                             ? 1.f : 0.f;
        // ---- stage h_inflows + h_self as swizzled bf16 ----
        {
            const float4* src = (const float4*)(hin_g + (size_t)nb * KI * H);
            float4 r0[8];
            #pragma unroll
            for (int i = 0; i < 8; ++i) r0[i] = src[t + i * 256];
            float4 hv = ((const float4*)(hself_g + (size_t)nb * H))[t];
            #pragma unroll
            for (int i = 0; i < 8; ++i) {
                int e = (t + i * 256) * 4, row = e >> 7, col = e & 127;
                unsigned byte = (unsigned)(row * 256 + col * 2) ^ (unsigned)((row & 7) << 4);
                us4 pk = { bf(r0[i].x), bf(r0[i].y), bf(r0[i].z), bf(r0[i].w) };
                *(us4*)((char*)hin_s + byte) = pk;
            }
            {
                int e = t * 4, row = e >> 7, col = e & 127;
                unsigned byte = (unsigned)(row * 256 + col * 2) ^ (unsigned)((row & 7) << 4);
                us4 pk = { bf(hv.x), bf(hv.y), bf(hv.z), bf(hv.w) };
                *(us4*)((char*)hs_s + byte) = pk;
            }
        }
        __syncthreads();   // B1: tile staged

        // ---- MFMA: msgs, pregates, gh (B from registers) ----
        f32x4 accM[4][2], accP[4][2], accG[2];
        #pragma unroll
        for (int m = 0; m < 4; ++m)
            #pragma unroll
            for (int c = 0; c < 2; ++c) { accM[m][c] = (f32x4)0.f; accP[m][c] = (f32x4)0.f; }
        accG[0] = (f32x4)0.f; accG[1] = (f32x4)0.f;

        #pragma unroll
        for (int kk = 0; kk < 4; ++kk) {
            const int k0 = kk * 32 + lk * 8;
            bf16x8 am[4];
            #pragma unroll
            for (int m = 0; m < 4; ++m) {
                int row = m * 16 + ln;
                unsigned byte = (unsigned)(row * 256 + k0 * 2) ^ (unsigned)((row & 7) << 4);
                am[m] = *(const bf16x8*)((const char*)hin_s + byte);
            }
            bf16x8 ah;
            {
                int row = ln & 7;
                unsigned byte = (unsigned)(row * 256 + k0 * 2) ^ (unsigned)((row & 7) << 4);
                ah = *(const bf16x8*)((const char*)hs_s + byte);
            }
            #pragma unroll
            for (int m = 0; m < 4; ++m)
                #pragma unroll
                for (int c = 0; c < 2; ++c) {
                    accM[m][c] = MFMA16(am[m], Bn[c][kk], accM[m][c]);
                    accP[m][c] = MFMA16(am[m], Ba[c][kk], accP[m][c]);
                }
            accG[0] = MFMA16(ah, Bb[0][kk], accG[0]);
            accG[1] = MFMA16(ah, Bb[1][kk], accG[1]);
        }

        #pragma unroll
        for (int c = 0; c < 2; ++c)
            #pragma unroll
            for (int r = 0; r < 4; ++r) {
                int row = lk * 4 + r;
                if (row < 8) gh_s[row][cbase + c * 16 + ln] = accG[c][r];
            }
        __syncthreads();   // B2: gh visible, hin_s reads done

        // ---- epilogue: sigmoid gate, mask, k-sum, stage nc ----
        #pragma unroll
        for (int m = 0; m < 4; ++m) {
            const int node = 2 * m + (lk >> 1);
            #pragma unroll
            for (int c = 0; c < 2; ++c) {
                const int col = cbase + c * 16 + ln;
                const float bgc = c ? bg1 : bg0;
                const float ghv = gh_s[node][col];
                float sum = 0.f;
                #pragma unroll
                for (int r = 0; r < 4; ++r) {
                    int row = m * 16 + lk * 4 + r;
                    float g = sigmoidf_(accP[m][c][r] + ghv + bgc);
                    sum += valid_s[row] * g * accM[m][c][r];
                }
                sum += __shfl_xor(sum, 16);
                if ((l & 16) == 0) ncs[(2 * m + (l >> 5)) * H + col] = bf(sum);
            }
        }
        __syncthreads();   // B3: ncs visible; all valid_s/gh_s reads done

        {   // coalesced bf16 nc write (ncs consumed into regs before store)
            int e = t * 4, node = e >> 7, col = e & 127;
            us4 v = *(const us4*)(ncs + e);
            *(us4*)(ncb + (size_t)(nb + node) * nc_stride + col) = v;
        }
        // no 4th barrier: next-iter writes (valid_s/hin_s/hs_s) are fenced by
        // B3; ncs is next written only after next B2.
    }
}

// ---------------------------------------------------------------------------
// LSTM via MFMA. 32 nodes/block, 512 threads (8 waves), low-register design:
// wave w owns z-cols [w*16, w*16+16) of ALL 4 gates -> acc = 2x4 f32x4.
// ---------------------------------------------------------------------------
__global__ __launch_bounds__(512, 4) void k_lstm_mfma(
    const float* __restrict__ x_g, const float* __restrict__ hself_g,
    const float* __restrict__ cself_g, const float* __restrict__ stat_g,
    const unsigned short* __restrict__ ncb, int nc_stride,
    const unsigned short* __restrict__ WpB, const float* __restrict__ bp,
    const float* __restrict__ lnw, const float* __restrict__ lnb,
    float* __restrict__ h_out, float* __restrict__ c_out)
{
    __shared__ char smem[MB_LSTM * CPAD * 2];      // 21KB
    unsigned short* comb = (unsigned short*)smem;  // [32][328] bf16
    float (*hpre)[132] = (float(*)[132])smem;      // union after GEMM

    const int t = threadIdx.x;
    const int nb = blockIdx.x * MB_LSTM;
    const int w = t >> 6, l = t & 63, ln = l & 15, lk = l >> 4;
    const int hcol = w * 16 + ln;

    if (t < 256) {  // x
        int e = t * 4, row = e >> 5, col = e & 31;
        us4 pk = { 0, 0, 0, 0 };
        if (nb + row < NN) {
            float4 v = ((const float4*)(x_g + (size_t)nb * XD))[t];
            pk = us4{ bf(v.x), bf(v.y), bf(v.z), bf(v.w) };
        }
        *(us4*)(comb + row * CPAD + col) = pk;
    }
    #pragma unroll
    for (int i = 0; i < 2; ++i) {  // h_self
        int p4 = t + i * 512;
        int e = p4 * 4, row = e >> 7, col = 32 + (e & 127);
        us4 pk = { 0, 0, 0, 0 };
        if (nb + row < NN) {
            float4 v = ((const float4*)(hself_g + (size_t)nb * H))[p4];
            pk = us4{ bf(v.x), bf(v.y), bf(v.z), bf(v.w) };
        }
        *(us4*)(comb + row * CPAD + col) = pk;
    }
    #pragma unroll
    for (int i = 0; i < 2; ++i) {  // nc (already bf16)
        int p4 = t + i * 512;
        int e = p4 * 4, row = e >> 7, col = e & 127;
        us4 v = { 0, 0, 0, 0 };
        if (nb + row < NN) v = *(const us4*)(ncb + (size_t)(nb + row) * nc_stride + col);
        *(us4*)(comb + row * CPAD + 160 + col) = v;
    }
    for (int i = t; i < MB_LSTM * SD; i += 512) {  // static
        int row = i / SD, col = i - row * SD;
        unsigned short v = 0;
        if (nb + row < NN) v = bf(stat_g[(size_t)(nb + row) * SD + col]);
        comb[row * CPAD + 288 + col] = v;
    }
    if (t < MB_LSTM * 5) {  // zero pad cols 315..319
        int row = t / 5, col = 315 + t % 5;
        comb[row * CPAD + col] = 0;
    }

    float cpre[8];
    #pragma unroll
    for (int m = 0; m < 2; ++m)
        #pragma unroll
        for (int r = 0; r < 4; ++r) {
            int node = m * 16 + lk * 4 + r;
            size_t n = (size_t)(nb + node);
            cpre[m * 4 + r] = (n < NN) ? cself_g[n * H + hcol] : 0.f;
        }
    __syncthreads();

    f32x4 acc[2][4];
    #pragma unroll
    for (int m = 0; m < 2; ++m)
        #pragma unroll
        for (int g = 0; g < 4; ++g) acc[m][g] = (f32x4)0.f;

    #pragma unroll
    for (int kk = 0; kk < 10; ++kk) {
        const int k0 = kk * 32 + lk * 8;
        bf16x8 a0 = *(const bf16x8*)(comb + ln * CPAD + k0);
        bf16x8 a1 = *(const bf16x8*)(comb + (16 + ln) * CPAD + k0);
        #pragma unroll
        for (int g = 0; g < 4; ++g) {
            bf16x8 b = *(const bf16x8*)(WpB + (size_t)(g * H + hcol) * CIN2 + k0);
            acc[0][g] = MFMA16(a0, b, acc[0][g]);
            acc[1][g] = MFMA16(a1, b, acc[1][g]);
        }
    }
    __syncthreads();

    {
        const float bi = bp[hcol], bff = bp[H + hcol];
        const float bo = bp[2 * H + hcol], bgg = bp[3 * H + hcol];
        #pragma unroll
        for (int m = 0; m < 2; ++m)
            #pragma unroll
            for (int r = 0; r < 4; ++r) {
                int node = m * 16 + lk * 4 + r;
                size_t n = (size_t)(nb + node);
                if (n < NN) {
                    float zi = acc[m][0][r] + bi;
                    float zf = acc[m][1][r] + bff;
                    float zo = acc[m][2][r] + bo;
                    float zg = acc[m][3][r] + bgg;
                    float cn = sigmoidf_(zf) * cpre[m * 4 + r] + sigmoidf_(zi) * tanhf_(zg);
                    c_out[n * H + hcol] = cn;
                    hpre[node][hcol] = sigmoidf_(zo) * tanhf_(cn);
                }
            }
    }
    __syncthreads();

    #pragma unroll
    for (int jj = 0; jj < 4; ++jj) {
        const int j = w * 4 + jj;
        const size_t n = (size_t)(nb + j);
        if (n < NN) {
            float a = hpre[j][l];
            float b = hpre[j][64 + l];
            float s = a + b, q = a * a + b * b;
            #pragma unroll
            for (int off = 1; off < 64; off <<= 1) {
                s += __shfl_xor(s, off);
                q += __shfl_xor(q, off);
            }
            float mu = s * (1.0f / 128.0f);
            float var = q * (1.0f / 128.0f) - mu * mu;
            float rstd = rsqrtf(var + 1e-5f);
            h_out[n * H + l]      = (a - mu) * rstd * lnw[l] + lnb[l];
            h_out[n * H + 64 + l] = (b - mu) * rstd * lnw[64 + l] + lnb[64 + l];
        }
    }
}

// ---------------------------------------------------------------------------
// f32 fallback path — used only if ws is too small.
// ---------------------------------------------------------------------------
__global__ __launch_bounds__(256) void k_nb_f32(
    const float* __restrict__ hself_g, const float* __restrict__ hin_g,
    const unsigned char* __restrict__ valid_raw,
    const float* __restrict__ Wn, const float* __restrict__ Wg,
    const float* __restrict__ bg, float* __restrict__ nc)
{
    __shared__ float4 hin_s[8 * KI * (H / 4)];
    __shared__ float4 hs_s[8 * (H / 4)];
    __shared__ int flag8;
    const int t = threadIdx.x;
    const int nb = blockIdx.x * 8;
    {
        int loc = 0;
        if (t < 64) {
            #pragma unroll
            for (int i = 0; i < 16; ++i) loc |= valid_raw[4 * (t * 16 + i) + 1];
        }
        int any = __any(loc != 0);
        if (t == 0) flag8 = any;
    }
    const float4* src_hin = (const float4*)(hin_g + (size_t)nb * KI * H);
    #pragma unroll
    for (int i = 0; i < 8; ++i) hin_s[t + i * 256] = src_hin[t + i * 256];
    hs_s[t] = ((const float4*)(hself_g + (size_t)nb * H))[t];
    __syncthreads();
    const int o = t & 127, g = t >> 7;
    float msg[4][KI], gat[4][KI], gh[4];
    #pragma unroll
    for (int j = 0; j < 4; ++j) {
        gh[j] = 0.f;
        #pragma unroll
        for (int k = 0; k < KI; ++k) { msg[j][k] = 0.f; gat[j][k] = 0.f; }
    }
    const float4* Wn4 = (const float4*)(Wn + (size_t)o * H);
    const float4* Wg4a = (const float4*)(Wg + (size_t)o * 2 * H);
    const float4* Wg4b = (const float4*)(Wg + (size_t)o * 2 * H + H);
    for (int d4 = 0; d4 < H / 4; ++d4) {
        float4 wn = Wn4[d4], w0 = Wg4a[d4], w1 = Wg4b[d4];
        #pragma unroll
        for (int j = 0; j < 4; ++j) {
            const int node = g * 4 + j;
            gh[j] += dot4_(w1, hs_s[node * 32 + d4]);
            #pragma unroll
            for (int k = 0; k < KI; ++k) {
                float4 hv = hin_s[(node * KI + k) * 32 + d4];
                msg[j][k] += dot4_(wn, hv);
                gat[j][k] += dot4_(w0, hv);
            }
        }
    }
    const float bgo = bg[o];
    const unsigned int* valid32 = (const unsigned int*)valid_raw;
    const int f8 = flag8;
    #pragma unroll
    for (int j = 0; j < 4; ++j) {
        const int n = nb + g * 4 + j;
        float acc = 0.f;
        #pragma unroll
        for (int k = 0; k < KI; ++k) {
            bool v = f8 ? (valid_raw[n * KI + k] != 0) : (valid32[n * KI + k] != 0u);
            if (v) acc += sigmoidf_(gat[j][k] + gh[j] + bgo) * msg[j][k];
        }
        nc[(size_t)n * H + o] = acc;
    }
}

__global__ __launch_bounds__(256) void k_lstm_f32(
    const float* __restrict__ x_g, const float* __restrict__ hself_g,
    const float* __restrict__ cself_g, const float* __restrict__ stat_g,
    const float* __restrict__ nc,
    const float* __restrict__ Ws, const float* __restrict__ bs,
    const float* __restrict__ Wl, const float* __restrict__ bl,
    const float* __restrict__ lnw, const float* __restrict__ lnb,
    float* __restrict__ h_out, float* __restrict__ c_out)
{
    __shared__ float4 comb4[16 * (CIN / 4)];
    __shared__ float zsh[16 * ZOUT];
    __shared__ float stat_s[16 * SD];
    float* combf = (float*)comb4;
    const int t = threadIdx.x;
    const int nb = blockIdx.x * 16;
    #pragma unroll
    for (int i = 0; i < 2; ++i) {
        int idx = t + i * 256;
        combf[(idx >> 5) * CIN + (idx & 31)] = x_g[(size_t)nb * XD + idx];
    }
    #pragma unroll
    for (int i = 0; i < 8; ++i) {
        int idx = t + i * 256;
        combf[(idx >> 7) * CIN + 32 + (idx & 127)] = hself_g[(size_t)nb * H + idx];
    }
    #pragma unroll
    for (int i = 0; i < 8; ++i) {
        int idx = t + i * 256;
        combf[(idx >> 7) * CIN + 160 + (idx & 127)] = nc[(size_t)nb * H + idx];
    }
    stat_s[t] = stat_g[(size_t)nb * SD + t];
    if (t < 16 * SD - 256) stat_s[t + 256] = stat_g[(size_t)nb * SD + t + 256];
    __syncthreads();
    {
        const int o = t & 127, jg = t >> 7;
        #pragma unroll
        for (int jj = 0; jj < 8; ++jj) {
            const int j = jg * 8 + jj;
            float s = bs[o];
            #pragma unroll
            for (int c = 0; c < SD; ++c) s += Ws[o * SD + c] * stat_s[j * SD + c];
            combf[j * CIN + 288 + o] = s;
        }
    }
    __syncthreads();
    float acc0[16], acc1[16];
    #pragma unroll
    for (int j = 0; j < 16; ++j) { acc0[j] = 0.f; acc1[j] = 0.f; }
    const float4* W0 = (const float4*)(Wl + (size_t)t * CIN);
    const float4* W1 = (const float4*)(Wl + (size_t)(t + 256) * CIN);
    for (int d4 = 0; d4 < CIN / 4; ++d4) {
        float4 w0 = W0[d4], w1 = W1[d4];
        #pragma unroll
        for (int j = 0; j < 16; ++j) {
            float4 cv = comb4[j * (CIN / 4) + d4];
            acc0[j] += dot4_(w0, cv);
            acc1[j] += dot4_(w1, cv);
        }
    }
    const float bl0 = bl[t], bl1 = bl[t + 256];
    #pragma unroll
    for (int j = 0; j < 16; ++j) {
        zsh[j * ZOUT + t] = acc0[j] + bl0;
        zsh[j * ZOUT + 256 + t] = acc1[j] + bl1;
    }
    __syncthreads();
    {
        const int h = t & 127, jg = t >> 7;
        #pragma unroll
        for (int jj = 0; jj < 8; ++jj) {
            const int j = jg * 8 + jj;
            const size_t n = (size_t)(nb + j);
            float zi = zsh[j * ZOUT + h];
            float zf = zsh[j * ZOUT + 128 + h];
            float zo = zsh[j * ZOUT + 256 + h];
            float zg = zsh[j * ZOUT + 384 + h];
            float cn = sigmoidf_(zf) * cself_g[n * H + h] + sigmoidf_(zi) * tanhf(zg);
            c_out[n * H + h] = cn;
            zsh[j * ZOUT + h] = sigmoidf_(zo) * tanhf(cn);
        }
    }
    __syncthreads();
    {
        const int w = t >> 6, lane = t & 63;
        #pragma unroll
        for (int jj = 0; jj < 4; ++jj) {
            const int j = w * 4 + jj;
            const size_t n = (size_t)(nb + j);
            float a = zsh[j * ZOUT + lane];
            float b = zsh[j * ZOUT + 64 + lane];
            float s = a + b, q = a * a + b * b;
            #pragma unroll
            for (int off = 1; off < 64; off <<= 1) {
                s += __shfl_xor(s, off);
                q += __shfl_xor(q, off);
            }
            float mu = s * (1.0f / 128.0f);
            float var = q * (1.0f / 128.0f) - mu * mu;
            float rstd = rsqrtf(var + 1e-5f);
            h_out[n * H + lane] = (a - mu) * rstd * lnw[lane] + lnb[lane];
            h_out[n * H + 64 + lane] = (b - mu) * rstd * lnw[64 + lane] + lnb[64 + lane];
        }
    }
}

extern "C" void kernel_launch(void* const* d_in, const int* in_sizes, int n_in,
                              void* d_out, int out_size, void* d_ws, size_t ws_size,
                              hipStream_t stream) {
    const float* x      = (const float*)d_in[0];
    const float* h_self = (const float*)d_in[1];
    const float* c_self = (const float*)d_in[2];
    const float* h_inf  = (const float*)d_in[3];
    const unsigned char* valid = (const unsigned char*)d_in[4];
    const float* statp  = (const float*)d_in[5];
    const float* Wn     = (const float*)d_in[6];
    const float* Wg     = (const float*)d_in[7];
    const float* bg     = (const float*)d_in[8];
    const float* Ws     = (const float*)d_in[9];
    const float* bs     = (const float*)d_in[10];
    const float* Wl     = (const float*)d_in[11];
    const float* bl     = (const float*)d_in[12];
    const float* lnw    = (const float*)d_in[13];
    const float* lnb    = (const float*)d_in[14];

    float* h_out = (float*)d_out;
    float* c_out = h_out + (size_t)NN * H;

    const size_t W_BYTES = (size_t)512 * CIN2 * 2 + 16384 * 2 + 32768 * 2 + 512 * 4;
    const size_t NC_BYTES = (size_t)NN * H * 2;

    if (ws_size >= W_BYTES) {
        char* p = (char*)d_ws;
        unsigned short* WpB = (unsigned short*)p;           p += (size_t)512 * CIN2 * 2;
        unsigned short* WnB = (unsigned short*)p;           p += 16384 * 2;
        unsigned short* WgB = (unsigned short*)p;           p += 32768 * 2;
        float* bp = (float*)p;                              p += 512 * 4;

        unsigned short* ncb;
        int nc_stride;
        if (ws_size >= W_BYTES + NC_BYTES + 64) {
            ncb = (unsigned short*)p;
            nc_stride = H;
        } else {
            ncb = (unsigned short*)h_out;
            nc_stride = 256;
        }

        k_prep<<<576, 256, 0, stream>>>(Wn, Wg, Wl, bl, Ws, bs,
                                        WnB, WgB, WpB, bp);
        k_nb_mfma<<<GRID_NB, 256, 0, stream>>>(h_self, h_inf, valid, WnB, WgB, bg,
                                               ncb, nc_stride);
        k_lstm_mfma<<<(NN + MB_LSTM - 1) / MB_LSTM, 512, 0, stream>>>(
            x, h_self, c_self, statp, ncb, nc_stride, WpB, bp,
            lnw, lnb, h_out, c_out);
    } else {
        float* nc_buf = (ws_size >= (size_t)NN * H * sizeof(float))
                            ? (float*)d_ws : h_out;
        k_nb_f32<<<NN / 8, 256, 0, stream>>>(h_self, h_inf, valid, Wn, Wg, bg, nc_buf);
        k_lstm_f32<<<NN / 16, 256, 0, stream>>>(x, h_self, c_self, statp, nc_buf,
                                                Ws, bs, Wl, bl, lnw, lnb, h_out, c_out);
    }
}